// Round 1
// baseline (240.755 us; speedup 1.0000x reference)
//
#include <hip/hip_runtime.h>

typedef float f32x4 __attribute__((ext_vector_type(4)));
typedef __bf16 bf16x8 __attribute__((ext_vector_type(8)));
typedef unsigned short u16;

#define DEVFN __device__ __forceinline__

DEVFN u16 f2bf(float f) {
    unsigned u = __builtin_bit_cast(unsigned, f);
    u += 0x7fffu + ((u >> 16) & 1u);
    return (u16)(u >> 16);
}
DEVFN float bf2f(u16 h) {
    unsigned u = ((unsigned)h) << 16;
    return __builtin_bit_cast(float, u);
}

DEVFN void gl2lds16(const void* g, void* l) {
    __builtin_amdgcn_global_load_lds(
        (const __attribute__((address_space(1))) void*)g,
        (__attribute__((address_space(3))) void*)l, 16, 0, 0);
}

// ---------------- fp32 -> bf16 convert (vectorized, 8 elems/thread) ----------------
__global__ void k_cvt(const float* __restrict__ src, u16* __restrict__ dst, int n8) {
    int t = blockIdx.x * blockDim.x + threadIdx.x;
    if (t >= n8) return;
    const float4* s = (const float4*)src;
    float4 a = s[2 * t], b = s[2 * t + 1];
    ushort4 r0 = { f2bf(a.x), f2bf(a.y), f2bf(a.z), f2bf(a.w) };
    ushort4 r1 = { f2bf(b.x), f2bf(b.y), f2bf(b.z), f2bf(b.w) };
    ((ushort4*)dst)[2 * t] = r0;
    ((ushort4*)dst)[2 * t + 1] = r1;
}

// ---------------- DFT tables ----------------
// F2[128][128]: rows 0-63  = cos(2*pi*m*n/128)   (Re of rfft)
//               rows 64-127= -sin(2*pi*m*n/128)  (Im of rfft)
// G[128][128] (irfft incl. 1/(N*D^2) scale): G[n][m]    =  c_m*s*cos(2*pi*m*n/128)
//                                            G[n][64+m] = -c_m*s*sin(2*pi*m*n/128)
__global__ void k_tables(u16* __restrict__ F2, u16* __restrict__ G) {
    int t = blockIdx.x * 256 + threadIdx.x; // 0..32767
    int which = t >> 14;
    int r = (t >> 7) & 127, c = t & 127;
    const float TWO_PI_128 = 6.283185307179586f / 128.f;
    if (which == 0) {
        int m = r & 63;
        int ph = (m * c) & 127;           // exact periodic reduction
        float ang = (float)ph * TWO_PI_128;
        float v = (r < 64) ? cosf(ang) : -sinf(ang);
        F2[r * 128 + c] = f2bf(v);
    } else {
        int m = c & 63;
        int ph = (m * r) & 127;
        float ang = (float)ph * TWO_PI_128;
        float cm = (m == 0) ? 1.f : 2.f;
        const float s = 1.f / (128.f * 512.f * 512.f);
        float v = (c < 64) ? cm * s * cosf(ang) : -cm * s * sinf(ang);
        G[r * 128 + c] = f2bf(v);
    }
}

// ---------------- generic 128x128x64 NT bf16 MFMA GEMM ----------------
// C[m,n] = sum_k A[m,k]*B[n,k];  A:[M,K] row-major (lda), B:[N,K] row-major (ldb)
// MODE 0: C0 bf16 = acc + bias[col]                         (e = X@Wlin^T + b_lin)
// MODE 1: cols<512 -> qT[b][col][n], <1024 -> kT, else T[row][col-1024]=acc+bias  (q/k/add)
// MODE 2: C0 bf16 [bz*sC + row*ldc + col]
// MODE 3: Cf fp32 [bz*sC + row*ldc + col]
// MODE 4: C0 bf16 accumulate (T += irfft result)
template<int MODE>
__global__ __launch_bounds__(256)
void gemm128(const u16* __restrict__ A, const u16* __restrict__ B,
             u16* __restrict__ C0, u16* __restrict__ C1, u16* __restrict__ C2,
             float* __restrict__ Cf, const float* __restrict__ bias,
             int K, int lda, int ldb, int ldc, long sA, long sB, long sC) {
    __shared__ __align__(16) u16 As[128 * 64];
    __shared__ __align__(16) u16 Bs[128 * 64];
    const int tid = threadIdx.x, wv = tid >> 6, ln = tid & 63;
    const long bz = blockIdx.z;
    const u16* Ab = A + bz * sA + (long)(blockIdx.y * 128) * lda;
    const u16* Bb = B + bz * sB + (long)(blockIdx.x * 128) * ldb;
    const int wm = (wv >> 1) * 64, wn = (wv & 1) * 64;
    f32x4 acc[4][4] = {};

    for (int k0 = 0; k0 < K; k0 += 64) {
        #pragma unroll
        for (int i = 0; i < 4; i++) {
            int chunk = i * 256 + tid;
            int row = chunk >> 3, kp = (chunk & 7) * 8;
            gl2lds16(Ab + (long)row * lda + k0 + kp, &As[(i * 256 + wv * 64) * 8]);
        }
        #pragma unroll
        for (int i = 0; i < 4; i++) {
            int chunk = i * 256 + tid;
            int row = chunk >> 3, kp = (chunk & 7) * 8;
            gl2lds16(Bb + (long)row * ldb + k0 + kp, &Bs[(i * 256 + wv * 64) * 8]);
        }
        __syncthreads();
        #pragma unroll
        for (int kk = 0; kk < 2; kk++) {
            bf16x8 af[4], bfr[4];
            const int rr = ln & 15, ks = kk * 32 + (ln >> 4) * 8;
            #pragma unroll
            for (int m = 0; m < 4; m++) af[m]  = *(const bf16x8*)&As[(wm + m * 16 + rr) * 64 + ks];
            #pragma unroll
            for (int n = 0; n < 4; n++) bfr[n] = *(const bf16x8*)&Bs[(wn + n * 16 + rr) * 64 + ks];
            #pragma unroll
            for (int m = 0; m < 4; m++)
                #pragma unroll
                for (int n = 0; n < 4; n++)
                    acc[m][n] = __builtin_amdgcn_mfma_f32_16x16x32_bf16(af[m], bfr[n], acc[m][n], 0, 0, 0);
        }
        __syncthreads();
    }

    const int fq = ln >> 4, fr = ln & 15;
    #pragma unroll
    for (int m = 0; m < 4; m++)
        #pragma unroll
        for (int n = 0; n < 4; n++)
            #pragma unroll
            for (int j = 0; j < 4; j++) {
                int row = blockIdx.y * 128 + wm + m * 16 + fq * 4 + j;
                int col = blockIdx.x * 128 + wn + n * 16 + fr;
                float v = acc[m][n][j];
                if constexpr (MODE == 0) {
                    C0[(long)row * ldc + col] = f2bf(v + bias[col]);
                } else if constexpr (MODE == 1) {
                    int b = row >> 7, nn = row & 127;
                    if (col < 512)        C0[(long)b * 65536 + (long)col * 128 + nn] = f2bf(v);
                    else if (col < 1024)  C1[(long)b * 65536 + (long)(col - 512) * 128 + nn] = f2bf(v);
                    else                  C2[(long)row * 512 + (col - 1024)] = f2bf(v + bias[col - 1024]);
                } else if constexpr (MODE == 2) {
                    C0[bz * sC + (long)row * ldc + col] = f2bf(v);
                } else if constexpr (MODE == 3) {
                    Cf[bz * sC + (long)row * ldc + col] = v;
                } else { // MODE 4
                    long idx = bz * sC + (long)row * ldc + col;
                    C0[idx] = f2bf(bf2f(C0[idx]) + v);
                }
            }
}

// ---------------- complex tanh + build S_cat = [[re,-im],[im,re]] ----------------
__global__ void k_tanh(const float* __restrict__ SC, u16* __restrict__ S) {
    int t = blockIdx.x * 256 + threadIdx.x; // < 64*64*64
    int b = t >> 12, x = (t >> 6) & 63, y = t & 63;
    const float* C = SC + (long)b * 16384;
    float c00 = C[x * 128 + y];
    float c01 = C[x * 128 + 64 + y];
    float c10 = C[(64 + x) * 128 + y];
    float c11 = C[(64 + x) * 128 + 64 + y];
    float re = c00 - c11, im = c01 + c10;
    float tr, ti;
    float x2 = 2.f * re, y2 = 2.f * im;
    if (fabsf(x2) > 40.f) {            // tanh saturates; imag part ~ e^{-|x2|}
        tr = (re > 0.f) ? 1.f : -1.f;
        ti = 0.f;
    } else {
        float ex = expf(x2);
        float sh = 0.5f * (ex - 1.f / ex), ch = 0.5f * (ex + 1.f / ex);
        float sn, cs;
        __sincosf(y2, &sn, &cs);
        float d = ch + cs;
        tr = sh / d;
        ti = sn / d;
    }
    u16* Sb = S + (long)b * 16384;
    u16 hr = f2bf(tr), hi = f2bf(ti), hin = f2bf(-ti);
    Sb[x * 128 + y] = hr;
    Sb[x * 128 + 64 + y] = hin;
    Sb[(64 + x) * 128 + y] = hi;
    Sb[(64 + x) * 128 + 64 + y] = hr;
}

// ---------------- final GEMM: partials[ch][64][1024] = T[64,kchunk] @ Wf[1024,kchunk]^T ----------------
// A = T bf16 via global_load_lds; B = W_final fp32 -> bf16 in-register during staging.
__global__ __launch_bounds__(256)
void gemm_final(const u16* __restrict__ T, const float* __restrict__ Wf, float* __restrict__ part) {
    __shared__ __align__(16) u16 As[64 * 64];
    __shared__ __align__(16) u16 Bs[64 * 64];
    const int tid = threadIdx.x, wv = tid >> 6, ln = tid & 63;
    const int bn = blockIdx.x * 64;
    const long kbase = (long)blockIdx.y * 1024;
    const int wm = (wv >> 1) * 32, wn = (wv & 1) * 32;
    f32x4 acc[2][2] = {};

    for (int k0 = 0; k0 < 1024; k0 += 64) {
        #pragma unroll
        for (int i = 0; i < 2; i++) {
            int chunk = i * 256 + tid;
            int row = chunk >> 3, kp = (chunk & 7) * 8;
            gl2lds16(T + (long)row * 65536 + kbase + k0 + kp, &As[(i * 256 + wv * 64) * 8]);
        }
        #pragma unroll
        for (int i = 0; i < 4; i++) {
            int idx = i * 256 + tid;
            int row = idx >> 4, kp = (idx & 15) * 4;
            float4 v = *(const float4*)&Wf[(long)(bn + row) * 65536 + kbase + k0 + kp];
            ushort4 r = { f2bf(v.x), f2bf(v.y), f2bf(v.z), f2bf(v.w) };
            *(ushort4*)&Bs[row * 64 + kp] = r;
        }
        __syncthreads();
        #pragma unroll
        for (int kk = 0; kk < 2; kk++) {
            bf16x8 af[2], bfr[2];
            const int rr = ln & 15, ks = kk * 32 + (ln >> 4) * 8;
            #pragma unroll
            for (int m = 0; m < 2; m++) af[m]  = *(const bf16x8*)&As[(wm + m * 16 + rr) * 64 + ks];
            #pragma unroll
            for (int n = 0; n < 2; n++) bfr[n] = *(const bf16x8*)&Bs[(wn + n * 16 + rr) * 64 + ks];
            #pragma unroll
            for (int m = 0; m < 2; m++)
                #pragma unroll
                for (int n = 0; n < 2; n++)
                    acc[m][n] = __builtin_amdgcn_mfma_f32_16x16x32_bf16(af[m], bfr[n], acc[m][n], 0, 0, 0);
        }
        __syncthreads();
    }

    const int fq = ln >> 4, fr = ln & 15;
    #pragma unroll
    for (int m = 0; m < 2; m++)
        #pragma unroll
        for (int n = 0; n < 2; n++)
            #pragma unroll
            for (int j = 0; j < 4; j++) {
                int row = wm + m * 16 + fq * 4 + j;
                int col = bn + wn + n * 16 + fr;
                part[(long)blockIdx.y * 65536 + (long)row * 1024 + col] = acc[m][n][j];
            }
}

__global__ void k_reduce(const float* __restrict__ part, const float* __restrict__ bias,
                         float* __restrict__ out) {
    int t = blockIdx.x * 256 + threadIdx.x; // < 65536
    float s = bias[t & 1023];
    #pragma unroll 8
    for (int ch = 0; ch < 64; ch++) s += part[(long)ch * 65536 + t];
    out[t] = s;
}

// ---------------- workspace layout (bytes) ----------------
static const size_t MB = 1048576;
static const size_t OFF_T      = 0;          // [8192][512] bf16, 8MB   (add path + fourier, final A)
static const size_t OFF_QT     = 8 * MB;     // [64][512][128] bf16, 8MB; reused: xqkv_em
static const size_t OFF_KT     = 16 * MB;    // [64][512][128] bf16, 8MB; reused: scoresC fp32 (4MB)
static const size_t OFF_SCAT   = 20 * MB;    // [64][128][128] bf16, 2MB
static const size_t OFF_XB     = 24 * MB;    // X bf16 16MB; reused: kft_em @24, kft_me @32
static const size_t OFF_KFT_EM = 24 * MB;    // [64][512][128] bf16, 8MB
static const size_t OFF_KFT_ME = 32 * MB;    // [64][128][512] bf16, 8MB
static const size_t OFF_EB     = 40 * MB;    // e bf16 [8192][512] 8MB; reused: qft_me
static const size_t OFF_QFT_ME = 40 * MB;    // [64][128][512] bf16, 8MB
static const size_t OFF_WLIN   = 48 * MB;    // [512][1024] bf16, 1MB
static const size_t OFF_WCAT   = 49 * MB;    // [1536][512] bf16, 1.5MB
static const size_t OFF_F2     = 50 * MB + 512 * 1024;
static const size_t OFF_G      = OFF_F2 + 32768;
static const size_t OFF_PART   = 8 * MB;     // [64][64][1024] fp32, 16MB (over QT/KT, both dead)

extern "C" void kernel_launch(void* const* d_in, const int* in_sizes, int n_in,
                              void* d_out, int out_size, void* d_ws, size_t ws_size,
                              hipStream_t stream) {
    const float* X      = (const float*)d_in[0]; // [64,128,1024]
    const float* W_lin  = (const float*)d_in[1]; // [512,1024]
    const float* b_lin  = (const float*)d_in[2]; // [512]
    const float* Wq     = (const float*)d_in[3]; // [512,512]
    const float* Wk     = (const float*)d_in[4]; // [512,512]
    const float* W_add  = (const float*)d_in[5]; // [512,512]
    const float* b_add  = (const float*)d_in[6]; // [512]
    const float* Wf     = (const float*)d_in[7]; // [1024,65536]
    const float* b_fin  = (const float*)d_in[8]; // [1024]
    float* out = (float*)d_out;

    char* ws = (char*)d_ws;
    u16* T       = (u16*)(ws + OFF_T);
    u16* qT      = (u16*)(ws + OFF_QT);
    u16* kT      = (u16*)(ws + OFF_KT);
    float* scC   = (float*)(ws + OFF_KT);
    u16* Scat    = (u16*)(ws + OFF_SCAT);
    u16* Xb      = (u16*)(ws + OFF_XB);
    u16* kft_em  = (u16*)(ws + OFF_KFT_EM);
    u16* kft_me  = (u16*)(ws + OFF_KFT_ME);
    u16* eb      = (u16*)(ws + OFF_EB);
    u16* qft_me  = (u16*)(ws + OFF_QFT_ME);
    u16* xqkv_em = (u16*)(ws + OFF_QT);
    u16* Wlin_b  = (u16*)(ws + OFF_WLIN);
    u16* Wcat_b  = (u16*)(ws + OFF_WCAT);
    u16* F2      = (u16*)(ws + OFF_F2);
    u16* G       = (u16*)(ws + OFF_G);
    float* part  = (float*)(ws + OFF_PART);

    // 1. conversions + tables
    k_cvt<<<4096, 256, 0, stream>>>(X, Xb, 1048576);
    k_cvt<<<256, 256, 0, stream>>>(W_lin, Wlin_b, 65536);
    k_cvt<<<128, 256, 0, stream>>>(Wq,    Wcat_b,           32768);
    k_cvt<<<128, 256, 0, stream>>>(Wk,    Wcat_b + 262144,  32768);
    k_cvt<<<128, 256, 0, stream>>>(W_add, Wcat_b + 524288,  32768);
    k_tables<<<128, 256, 0, stream>>>(F2, G);

    // 2. e = X @ Wlin^T + b_lin  -> eb [8192][512]
    gemm128<0><<<dim3(4, 64, 1), 256, 0, stream>>>(Xb, Wlin_b, eb, nullptr, nullptr, nullptr,
                                                   b_lin, 1024, 1024, 1024, 512, 0, 0, 0);
    // 3. q,k,add = e @ Wcat^T  -> qT, kT (transposed [b][e][n]), T = add path
    gemm128<1><<<dim3(12, 64, 1), 256, 0, stream>>>(eb, Wcat_b, qT, kT, T, nullptr,
                                                    b_add, 512, 512, 512, 0, 0, 0, 0);
    // 4. DFT:  qft_me[b][mcat][e] = F2 @ qT_b^T ; kft_me same ; kft_em[b][e][mcat] = qT-orientation
    gemm128<2><<<dim3(4, 1, 64), 256, 0, stream>>>(F2, qT, qft_me, nullptr, nullptr, nullptr,
                                                   nullptr, 128, 128, 128, 512, 0, 65536, 65536);
    gemm128<2><<<dim3(4, 1, 64), 256, 0, stream>>>(F2, kT, kft_me, nullptr, nullptr, nullptr,
                                                   nullptr, 128, 128, 128, 512, 0, 65536, 65536);
    gemm128<2><<<dim3(1, 4, 64), 256, 0, stream>>>(kT, F2, kft_em, nullptr, nullptr, nullptr,
                                                   nullptr, 128, 128, 128, 128, 65536, 0, 65536);
    // 5. scores (pre-tanh, block form): scC[b][128][128] = qft_me @ kft_me^T
    gemm128<3><<<dim3(1, 1, 64), 256, 0, stream>>>(qft_me, kft_me, nullptr, nullptr, nullptr, scC,
                                                   nullptr, 512, 512, 512, 128, 65536, 65536, 16384);
    // 6. complex tanh -> S_cat [[re,-im],[im,re]]
    k_tanh<<<1024, 256, 0, stream>>>(scC, Scat);
    // 7. xqkv_em[b][e][xcat] = kft_em @ S_cat^T
    gemm128<2><<<dim3(1, 4, 64), 256, 0, stream>>>(kft_em, Scat, xqkv_em, nullptr, nullptr, nullptr,
                                                   nullptr, 128, 128, 128, 128, 65536, 16384, 65536);
    // 8. T[b][n][e] += G @ xqkv_em^T   (irfft incl. 1/(N*D^2))
    gemm128<4><<<dim3(4, 1, 64), 256, 0, stream>>>(G, xqkv_em, T, nullptr, nullptr, nullptr,
                                                   nullptr, 128, 128, 128, 512, 0, 65536, 65536);
    // 9. final: partials over 64 K-chunks, then reduce (+ b_final)
    gemm_final<<<dim3(16, 64), 256, 0, stream>>>(T, Wf, part);
    k_reduce<<<256, 256, 0, stream>>>(part, b_fin, out);
}